// Round 4
// baseline (9409.125 us; speedup 1.0000x reference)
//
#include <hip/hip_runtime.h>
#include <cmath>

// ---- problem constants ----
#define NB 16
#define CC 32          // channels per dictionary (A and B each)
#define HH 256
#define WW 256
#define DD 250         // 256 - 7 + 1
#define ALPHA 2.0f     // 1 + 1/RHO
#define INVL 0.1f      // 1/L
#define THR 0.01f      // LAM/L

#define IMG_SZ (HH*WW)                       // 65536
#define IMG_TOT (NB*IMG_SZ)                  // 1,048,576
#define FLD_SZ (DD*DD)                       // 62,500
#define FLD_TOT ((size_t)NB*CC*FLD_SZ)       // 32,000,000

#define LRS 260                              // lres row stride (bank-padded)

// force a block-uniform float into an SGPR (weights -> s-operand of v_fma)
__device__ __forceinline__ float rfl(float x) {
    return __int_as_float(__builtin_amdgcn_readfirstlane(__float_as_int(x)));
}

// ---------------------------------------------------------------------------
// k_update v4: TWO channels per block. grid = (32 pairs, 16 ptiles, 16 n).
// Stage res rows [p0..p0+21] x 256 in LDS (stride 260 = bank-padded);
// weights in SGPRs; 32-bit global offsets (saddr addressing);
// thread computes 4 rows x 4 cols per channel.
//   tmp = s_cur + cm*(s_cur - s_old); v = tmp + conv(res,W)*INVL;
//   u-field: soft-threshold; s_next (aliases s_old) = v.
// ---------------------------------------------------------------------------
__global__ __launch_bounds__(256) void k_update(
    const float* __restrict__ rin,
    const float* sx_cur, const float* sx_old,
    const float* su_cur, const float* su_old,
    float* sx_next, float* su_next,
    const float* __restrict__ Afil, const float* __restrict__ Bfil,
    float cmom, int first)
{
    __shared__ float lres[22*LRS + 8];

    const int pr  = blockIdx.x;              // 0..31 (0-15: x/A, 16-31: u/B)
    const int p0  = blockIdx.y * 16;
    const int n   = blockIdx.z;
    const int tid = threadIdx.x;
    const bool isx = (pr < 16);
    const int  cf0 = (isx ? pr : pr - 16) * 2;

    const float* rbase = rin + n * IMG_SZ;
#pragma unroll
    for (int it = 0; it < 6; ++it) {
        int idx = tid + it*256;
        if (idx < 22*64) {
            int r = idx >> 6, c4 = (idx & 63) << 2;
            int gr = p0 + r;
            float4 v = make_float4(0.f,0.f,0.f,0.f);
            if (gr < HH) v = *(const float4*)(rbase + (unsigned)(gr*WW + c4));
            *(float4*)&lres[r*LRS + c4] = v;
        }
    }
    if (tid < 8) lres[22*LRS + tid] = 0.f;
    __syncthreads();

    const int tq = tid & 63;
    const int pg = tid >> 6;
    const int q4 = tq << 2;

    const float* scur  = isx ? sx_cur  : su_cur;
    const float* sold  = isx ? sx_old  : su_old;
    float*       snext = isx ? sx_next : su_next;
    const float* Wd    = isx ? Afil : Bfil;
    const bool momentum = (!first) && (cmom != 0.0f);
    const bool plain    = (!first) && (cmom == 0.0f);

    for (int ch = 0; ch < 2; ++ch) {
        const int cf = cf0 + ch;
        const float* Wp = Wd + cf*49;
        float wt[7][7];
#pragma unroll
        for (int a = 0; a < 7; ++a)
#pragma unroll
            for (int b = 0; b < 7; ++b)
                wt[a][b] = rfl(Wp[a*7 + b]);

        float acc[4][4];
#pragma unroll
        for (int k = 0; k < 4; ++k)
#pragma unroll
            for (int j = 0; j < 4; ++j) acc[k][j] = 0.f;

#pragma unroll
        for (int rr = 0; rr < 10; ++rr) {
            const float4* lp = (const float4*)&lres[(pg*4 + rr)*LRS + q4];
            float4 A0 = lp[0], A1 = lp[1], A2 = lp[2];
            float win[12] = {A0.x,A0.y,A0.z,A0.w, A1.x,A1.y,A1.z,A1.w,
                             A2.x,A2.y,A2.z,A2.w};
#pragma unroll
            for (int k = 0; k < 4; ++k) {
                const int a = rr - k;
                if (a >= 0 && a < 7) {
#pragma unroll
                    for (int b = 0; b < 7; ++b) {
                        float wv = wt[a][b];
#pragma unroll
                        for (int j = 0; j < 4; ++j)
                            acc[k][j] += win[b + j] * wv;
                    }
                }
            }
        }

        const unsigned base = (unsigned)((n*CC + cf) * FLD_SZ);
#pragma unroll
        for (int k = 0; k < 4; ++k) {
            int p = p0 + pg*4 + k;
            if (p < DD) {
                unsigned off = base + (unsigned)(p*DD + q4);
                if (q4 <= 248) {
                    float t0 = 0.f, t1 = 0.f;
                    if (momentum) {
                        float2 sc = *(const float2*)(scur + off);
                        float2 so = *(const float2*)(sold + off);
                        t0 = sc.x + cmom*(sc.x - so.x);
                        t1 = sc.y + cmom*(sc.y - so.y);
                    } else if (plain) {
                        float2 sc = *(const float2*)(scur + off);
                        t0 = sc.x; t1 = sc.y;
                    }
                    float v0 = t0 + acc[k][0]*INVL;
                    float v1 = t1 + acc[k][1]*INVL;
                    if (!isx) {
                        float a0 = fabsf(v0) - THR; a0 = a0 > 0.f ? a0 : 0.f;
                        v0 = (v0 > 0.f) ? a0 : ((v0 < 0.f) ? -a0 : 0.f);
                        float a1 = fabsf(v1) - THR; a1 = a1 > 0.f ? a1 : 0.f;
                        v1 = (v1 > 0.f) ? a1 : ((v1 < 0.f) ? -a1 : 0.f);
                    }
                    *(float2*)(snext + off) = make_float2(v0, v1);
                }
                if (q4 <= 246) {
                    float t2 = 0.f, t3 = 0.f;
                    if (momentum) {
                        float2 sc = *(const float2*)(scur + off + 2);
                        float2 so = *(const float2*)(sold + off + 2);
                        t2 = sc.x + cmom*(sc.x - so.x);
                        t3 = sc.y + cmom*(sc.y - so.y);
                    } else if (plain) {
                        float2 sc = *(const float2*)(scur + off + 2);
                        t2 = sc.x; t3 = sc.y;
                    }
                    float v2 = t2 + acc[k][2]*INVL;
                    float v3 = t3 + acc[k][3]*INVL;
                    if (!isx) {
                        float a2 = fabsf(v2) - THR; a2 = a2 > 0.f ? a2 : 0.f;
                        v2 = (v2 > 0.f) ? a2 : ((v2 < 0.f) ? -a2 : 0.f);
                        float a3 = fabsf(v3) - THR; a3 = a3 > 0.f ? a3 : 0.f;
                        v3 = (v3 > 0.f) ? a3 : ((v3 < 0.f) ? -a3 : 0.f);
                    }
                    *(float2*)(snext + off + 2) = make_float2(v2, v3);
                }
            }
        }
    }
}

// ---------------------------------------------------------------------------
// k_convT v4: channel-group split partials; 32-bit offsets; SGPR weights.
// grid = (16 htiles, 2 fields, NB*ngroups). Zero-padded 22x264 LDS plane.
// ---------------------------------------------------------------------------
__global__ __launch_bounds__(256) void k_convT(
    const float* __restrict__ sx, const float* __restrict__ su,
    float* __restrict__ Xpart, float* __restrict__ Upart,
    const float* __restrict__ Afil, const float* __restrict__ Bfil,
    int nc, int ngroups)
{
    __shared__ float st[22*264];

    const int h0  = blockIdx.x * 16;
    const int f   = blockIdx.y;
    const int zz  = blockIdx.z;
    const int g   = zz % ngroups;
    const int n   = zz / ngroups;
    const int c0  = g * nc;
    const int tid = threadIdx.x;

    const float* Sn = (f ? su : sx) + (unsigned)(n*CC*FLD_SZ);
    const float* Wb = f ? Bfil : Afil;
    float* O = (f ? Upart : Xpart) + (unsigned)((g*NB + n) * IMG_SZ);

    for (int i = tid; i < 22*14; i += 256) {
        int r = i / 14, j = i - r*14;
        st[r*264 + (j < 6 ? j : 250 + j)] = 0.f;
    }

    const int tw = tid & 63;
    const int hg = tid >> 6;
    const int w4 = tw << 2;

    float acc[4][4];
#pragma unroll
    for (int k = 0; k < 4; ++k)
#pragma unroll
        for (int j = 0; j < 4; ++j) acc[k][j] = 0.f;

    for (int cc2 = 0; cc2 < nc; ++cc2) {
        const int c = c0 + cc2;
        __syncthreads();
        const unsigned cbase = (unsigned)(c * FLD_SZ);
        for (int i = tid; i < 22*125; i += 256) {
            int r = i / 125, j = i - r*125;
            int sr = h0 - 6 + r;
            float2 v = make_float2(0.f, 0.f);
            if (sr >= 0 && sr < DD)
                v = *(const float2*)(Sn + cbase + (unsigned)(sr*DD + 2*j));
            *(float2*)&st[r*264 + 6 + 2*j] = v;
        }
        float wt[7][7];
#pragma unroll
        for (int a = 0; a < 7; ++a)
#pragma unroll
            for (int b = 0; b < 7; ++b)
                wt[a][b] = rfl(Wb[c*49 + a*7 + b]);
        __syncthreads();

#pragma unroll
        for (int rr = 0; rr < 10; ++rr) {
            const float4* lp = (const float4*)&st[(hg*4 + rr)*264 + w4];
            float4 A0 = lp[0], A1 = lp[1], A2 = lp[2];
            float win[12] = {A0.x,A0.y,A0.z,A0.w, A1.x,A1.y,A1.z,A1.w,
                             A2.x,A2.y,A2.z,A2.w};
#pragma unroll
            for (int k = 0; k < 4; ++k) {
                const int a = k + 6 - rr;
                if (a >= 0 && a < 7) {
#pragma unroll
                    for (int b = 0; b < 7; ++b) {
                        float wv = wt[a][b];
#pragma unroll
                        for (int j = 0; j < 4; ++j)
                            acc[k][j] += win[j - b + 6] * wv;
                    }
                }
            }
        }
    }

#pragma unroll
    for (int k = 0; k < 4; ++k) {
        int h = h0 + hg*4 + k;
        *(float4*)(O + (unsigned)(h*WW + w4)) =
            make_float4(acc[k][0], acc[k][1], acc[k][2], acc[k][3]);
    }
}

// ---------------------------------------------------------------------------
// k_res: reduce partials -> Xc/Uc; prev compacts = Xo/Uo; write compacts;
// emit res.
// ---------------------------------------------------------------------------
__global__ __launch_bounds__(256) void k_res(
    const float* __restrict__ y,
    const float* __restrict__ Xp, const float* __restrict__ Up,
    float* Xred, float* Ured,
    float* __restrict__ res, float cm, int nparts)
{
    int i = blockIdx.x*256 + threadIdx.x;
    if (i >= IMG_TOT/4) return;
    float4 xc = ((const float4*)Xp)[i];
    float4 uc = ((const float4*)Up)[i];
    for (int g = 1; g < nparts; ++g) {
        float4 t = ((const float4*)Xp)[(size_t)g*(IMG_TOT/4) + i];
        xc.x += t.x; xc.y += t.y; xc.z += t.z; xc.w += t.w;
        float4 s = ((const float4*)Up)[(size_t)g*(IMG_TOT/4) + i];
        uc.x += s.x; uc.y += s.y; uc.z += s.z; uc.w += s.w;
    }
    float4 xo = make_float4(0.f,0.f,0.f,0.f), uo = xo;
    if (cm != 0.0f) {
        xo = ((const float4*)Xred)[i];
        uo = ((const float4*)Ured)[i];
    }
    ((float4*)Xred)[i] = xc;
    ((float4*)Ured)[i] = uc;
    float4 yv = ((const float4*)y)[i];
    float cp = 1.0f + cm;
    float4 r;
    r.x = yv.x - ALPHA*(cp*xc.x - cm*xo.x) - (cp*uc.x - cm*uo.x);
    r.y = yv.y - ALPHA*(cp*xc.y - cm*xo.y) - (cp*uc.y - cm*uo.y);
    r.z = yv.z - ALPHA*(cp*xc.z - cm*xo.z) - (cp*uc.z - cm*uo.z);
    r.w = yv.w - ALPHA*(cp*xc.w - cm*xo.w) - (cp*uc.w - cm*uo.w);
    ((float4*)res)[i] = r;
}

// ---------------------------------------------------------------------------
// k_final: reduce gen-15 partials; yhat = X+U; Ax_hat = X; Bu_hat = U.
// ---------------------------------------------------------------------------
__global__ __launch_bounds__(256) void k_final(
    const float* Xp, const float* Up,
    float* yhat, float* axh, float* buh, int nparts)
{
    int i = blockIdx.x*256 + threadIdx.x;
    if (i >= IMG_TOT/4) return;
    float4 x = ((const float4*)Xp)[i];
    float4 u = ((const float4*)Up)[i];
    for (int g = 1; g < nparts; ++g) {
        float4 t = ((const float4*)Xp)[(size_t)g*(IMG_TOT/4) + i];
        x.x += t.x; x.y += t.y; x.z += t.z; x.w += t.w;
        float4 s = ((const float4*)Up)[(size_t)g*(IMG_TOT/4) + i];
        u.x += s.x; u.y += s.y; u.z += s.z; u.w += s.w;
    }
    float4 sm;
    sm.x = x.x + u.x; sm.y = x.y + u.y; sm.z = x.z + u.z; sm.w = x.w + u.w;
    ((float4*)yhat)[i] = sm;
    ((float4*)axh)[i]  = x;
    ((float4*)buh)[i]  = u;
}

extern "C" void kernel_launch(void* const* d_in, const int* in_sizes, int n_in,
                              void* d_out, int out_size, void* d_ws, size_t ws_size,
                              hipStream_t stream) {
    const float* y = (const float*)d_in[0];
    const float* A = (const float*)d_in[1];
    const float* B = (const float*)d_in[2];

    float* out  = (float*)d_out;
    float* yhat = out;                          // [IMG_TOT]
    float* xout = out + IMG_TOT;                // [FLD_TOT]
    float* uout = xout + FLD_TOT;               // [FLD_TOT]
    float* axh  = uout + FLD_TOT;               // [IMG_TOT]
    float* buh  = axh + IMG_TOT;                // [IMG_TOT]

    float* ws   = (float*)d_ws;
    float* Px0  = ws;                           // [FLD_TOT]
    float* Pu0  = Px0 + FLD_TOT;                // [FLD_TOT]
    float* Xred = Pu0 + FLD_TOT;                // [IMG_TOT]
    float* Ured = Xred + IMG_TOT;               // [IMG_TOT]

    int ngroups = 1;
    float* Xpart = axh;
    float* Upart = buh;
    size_t need4 = (2*FLD_TOT + 10*(size_t)IMG_TOT) * sizeof(float); // ~296 MB
    if (ws_size >= need4) {
        ngroups = 4;
        Xpart = Ured + IMG_TOT;                 // [4*IMG_TOT]
        Upart = Xpart + 4*(size_t)IMG_TOT;      // [4*IMG_TOT]
    }
    const int nc = CC / ngroups;

    float cv[15];
    {
        float t = 1.0f;
        for (int k = 0; k < 15; ++k) {
            float tn = (1.0f + sqrtf(1.0f + 4.0f*t*t)) * 0.5f;
            cv[k] = (t - 1.0f) / tn;
            t = tn;
        }
    }

    float* Px[2] = {Px0, xout};
    float* Pu[2] = {Pu0, uout};
    float* res   = yhat;

    dim3 blk(256);
    dim3 gU(32, 16, NB);                        // (channel pair, p-tile, n)
    dim3 gT(16, 2, NB*ngroups);                 // (h-tile, field, n*group)
    int  gE = (IMG_TOT/4 + 255)/256;

    k_update<<<gU, blk, 0, stream>>>(y, Px[0], Px[0], Pu[0], Pu[0],
                                     Px[1], Pu[1], A, B, 0.0f, 1);
    k_convT<<<gT, blk, 0, stream>>>(Px[1], Pu[1], Xpart, Upart, A, B, nc, ngroups);

    for (int t = 1; t < 15; ++t) {
        int cur = t & 1, nxt = cur ^ 1;
        float cm = cv[t-1];
        k_res<<<gE, blk, 0, stream>>>(y, Xpart, Upart, Xred, Ured, res, cm, ngroups);
        k_update<<<gU, blk, 0, stream>>>(res, Px[cur], Px[nxt], Pu[cur], Pu[nxt],
                                         Px[nxt], Pu[nxt], A, B, cm, 0);
        k_convT<<<gT, blk, 0, stream>>>(Px[nxt], Pu[nxt], Xpart, Upart, A, B, nc, ngroups);
    }

    k_final<<<gE, blk, 0, stream>>>(Xpart, Upart, yhat, axh, buh, ngroups);
}

// Round 5
// 6415.295 us; speedup vs baseline: 1.4667x; 1.4667x over previous
//
#include <hip/hip_runtime.h>
#include <cmath>

// ---- problem constants ----
#define NB 16
#define CC 32          // channels per dictionary (A and B each)
#define HH 256
#define WW 256
#define DD 250         // 256 - 7 + 1
#define ALPHA 2.0f     // 1 + 1/RHO
#define INVL 0.1f      // 1/L
#define THR 0.01f      // LAM/L

#define IMG_SZ (HH*WW)                       // 65536
#define IMG_TOT (NB*IMG_SZ)                  // 1,048,576
#define FLD_SZ (DD*DD)                       // 62,500
#define FLD_TOT ((size_t)NB*CC*FLD_SZ)       // 32,000,000

#define LRS 260                              // lres row stride (bank-padded)

// force a block-uniform float into an SGPR (weights -> s-operand of v_fma)
__device__ __forceinline__ float rfl(float x) {
    return __int_as_float(__builtin_amdgcn_readfirstlane(__float_as_int(x)));
}

__device__ __forceinline__ float sthr(float v) {
    float a = fabsf(v) - THR; a = a > 0.f ? a : 0.f;
    return (v > 0.f) ? a : ((v < 0.f) ? -a : 0.f);
}

// ---------------------------------------------------------------------------
// k_update v5: ONE channel per block (v3 structure). grid = (64, 16, 16).
// Phase 1: stage res rows [p0..p0+21] x 256 in LDS (stride 260, bank-padded).
// Phase 2: conv -> acc[4][4] in registers (weights in SGPRs).
// Phase 3: acc -> LDS flat [16][250] (overlays lres after sync).
// Phase 4: STREAMING epilogue over the flat 16x250 region: float4 loads of
//          s_cur/s_old + float4 store of s_next, fully coalesced & aligned
//          (channel base and p0*250 both 16B-aligned). No row branches.
// ---------------------------------------------------------------------------
__global__ __launch_bounds__(256) void k_update(
    const float* __restrict__ rin,
    const float* sx_cur, const float* sx_old,
    const float* su_cur, const float* su_old,
    float* sx_next, float* su_next,
    const float* __restrict__ Afil, const float* __restrict__ Bfil,
    float cmom, int first)
{
    __shared__ float smem[22*LRS + 8];       // lres; later overlaid by acc[4000]

    const int c   = blockIdx.x;              // 0..63 (0-31: x/A, 32-63: u/B)
    const int p0  = blockIdx.y * 16;
    const int n   = blockIdx.z;
    const int tid = threadIdx.x;
    const bool isx = (c < CC);
    const int  cf  = isx ? c : c - CC;

    // ---- phase 1: stage res tile ----
    const float* rbase = rin + (size_t)n * IMG_SZ;
#pragma unroll
    for (int it = 0; it < 6; ++it) {
        int idx = tid + it*256;
        if (idx < 22*64) {
            int r = idx >> 6, c4 = (idx & 63) << 2;
            int gr = p0 + r;
            float4 v = make_float4(0.f,0.f,0.f,0.f);
            if (gr < HH) v = *(const float4*)(rbase + gr*WW + c4);
            *(float4*)&smem[r*LRS + c4] = v;
        }
    }
    if (tid < 8) smem[22*LRS + tid] = 0.f;

    const float* Wp = (isx ? Afil : Bfil) + cf*49;
    float wt[7][7];
#pragma unroll
    for (int a = 0; a < 7; ++a)
#pragma unroll
        for (int b = 0; b < 7; ++b)
            wt[a][b] = rfl(Wp[a*7 + b]);

    __syncthreads();

    // ---- phase 2: conv ----
    const int tq = tid & 63;
    const int pg = tid >> 6;
    const int q4 = tq << 2;

    float acc[4][4];
#pragma unroll
    for (int k = 0; k < 4; ++k)
#pragma unroll
        for (int j = 0; j < 4; ++j) acc[k][j] = 0.f;

#pragma unroll
    for (int rr = 0; rr < 10; ++rr) {
        const float4* lp = (const float4*)&smem[(pg*4 + rr)*LRS + q4];
        float4 A0 = lp[0], A1 = lp[1], A2 = lp[2];
        float win[12] = {A0.x,A0.y,A0.z,A0.w, A1.x,A1.y,A1.z,A1.w,
                         A2.x,A2.y,A2.z,A2.w};
#pragma unroll
        for (int k = 0; k < 4; ++k) {
            const int a = rr - k;
            if (a >= 0 && a < 7) {
#pragma unroll
                for (int b = 0; b < 7; ++b) {
                    float wv = wt[a][b];
#pragma unroll
                    for (int j = 0; j < 4; ++j)
                        acc[k][j] += win[b + j] * wv;
                }
            }
        }
    }

    __syncthreads();   // all lres reads done; safe to overlay

    // ---- phase 3: acc -> LDS flat [16][250] ----
#pragma unroll
    for (int k = 0; k < 4; ++k) {
        int p = p0 + pg*4 + k;
        if (p < DD) {
            int lr = pg*4 + k;               // 0..15
            if (q4 <= 244)
                *(float4*)&smem[lr*250 + q4] =
                    make_float4(acc[k][0], acc[k][1], acc[k][2], acc[k][3]);
            else if (q4 == 248)
                *(float2*)&smem[lr*250 + q4] =
                    make_float2(acc[k][0], acc[k][1]);
            // q4 == 252: cols 252..255 don't exist
        }
    }
    __syncthreads();

    // ---- phase 4: streaming epilogue ----
    const int rows = (DD - p0 < 16) ? (DD - p0) : 16;   // 16 or 10
    const int nf4  = (rows * 250) >> 2;                 // 1000 or 625
    const size_t gb = ((size_t)n*CC + cf) * FLD_SZ + (size_t)p0 * DD;

    const float* scur  = (isx ? sx_cur  : su_cur)  + gb;
    const float* sold  = (isx ? sx_old  : su_old)  + gb;
    float*       snext = (isx ? sx_next : su_next) + gb;

    const bool momentum = (!first) && (cmom != 0.0f);
    const bool plain    = (!first) && (cmom == 0.0f);

    float4 av[4], scv[4], sov[4];
    bool ok[4];
#pragma unroll
    for (int j = 0; j < 4; ++j) {
        int i4 = tid + j*256;
        ok[j] = (i4 < nf4);
        if (ok[j]) {
            av[j] = *(const float4*)&smem[i4 << 2];
            if (momentum) {
                scv[j] = *(const float4*)(scur + (i4 << 2));
                sov[j] = *(const float4*)(sold + (i4 << 2));
            } else if (plain) {
                scv[j] = *(const float4*)(scur + (i4 << 2));
            }
        }
    }
#pragma unroll
    for (int j = 0; j < 4; ++j) {
        if (ok[j]) {
            float4 o;
            if (momentum) {
                o.x = scv[j].x + cmom*(scv[j].x - sov[j].x) + av[j].x*INVL;
                o.y = scv[j].y + cmom*(scv[j].y - sov[j].y) + av[j].y*INVL;
                o.z = scv[j].z + cmom*(scv[j].z - sov[j].z) + av[j].z*INVL;
                o.w = scv[j].w + cmom*(scv[j].w - sov[j].w) + av[j].w*INVL;
            } else if (plain) {
                o.x = scv[j].x + av[j].x*INVL;
                o.y = scv[j].y + av[j].y*INVL;
                o.z = scv[j].z + av[j].z*INVL;
                o.w = scv[j].w + av[j].w*INVL;
            } else {
                o.x = av[j].x*INVL; o.y = av[j].y*INVL;
                o.z = av[j].z*INVL; o.w = av[j].w*INVL;
            }
            if (!isx) {
                o.x = sthr(o.x); o.y = sthr(o.y);
                o.z = sthr(o.z); o.w = sthr(o.w);
            }
            *(float4*)(snext + (tid + j*256)*4) = o;
        }
    }
}

// ---------------------------------------------------------------------------
// k_convT (v3-proven): channel-group split partials; SGPR weights.
// grid = (16 htiles, 2 fields, NB*ngroups). Zero-padded 22x264 LDS plane.
// ---------------------------------------------------------------------------
__global__ __launch_bounds__(256) void k_convT(
    const float* __restrict__ sx, const float* __restrict__ su,
    float* __restrict__ Xpart, float* __restrict__ Upart,
    const float* __restrict__ Afil, const float* __restrict__ Bfil,
    int nc, int ngroups)
{
    __shared__ float st[22*264];

    const int h0  = blockIdx.x * 16;
    const int f   = blockIdx.y;
    const int zz  = blockIdx.z;
    const int g   = zz % ngroups;
    const int n   = zz / ngroups;
    const int c0  = g * nc;
    const int tid = threadIdx.x;

    const float* Sn = (f ? su : sx) + (size_t)n*CC*FLD_SZ;
    const float* Wb = f ? Bfil : Afil;
    float* O = (f ? Upart : Xpart) + ((size_t)g*NB + n) * IMG_SZ;

    for (int i = tid; i < 22*14; i += 256) {
        int r = i / 14, j = i - r*14;
        st[r*264 + (j < 6 ? j : 250 + j)] = 0.f;
    }

    const int tw = tid & 63;
    const int hg = tid >> 6;
    const int w4 = tw << 2;

    float acc[4][4];
#pragma unroll
    for (int k = 0; k < 4; ++k)
#pragma unroll
        for (int j = 0; j < 4; ++j) acc[k][j] = 0.f;

    for (int cc2 = 0; cc2 < nc; ++cc2) {
        const int c = c0 + cc2;
        __syncthreads();
        const float* Sp = Sn + (size_t)c * FLD_SZ;
        for (int i = tid; i < 22*125; i += 256) {
            int r = i / 125, j = i - r*125;
            int sr = h0 - 6 + r;
            float2 v = make_float2(0.f, 0.f);
            if (sr >= 0 && sr < DD) v = *(const float2*)(Sp + (size_t)sr*DD + 2*j);
            *(float2*)&st[r*264 + 6 + 2*j] = v;
        }
        float wt[7][7];
#pragma unroll
        for (int a = 0; a < 7; ++a)
#pragma unroll
            for (int b = 0; b < 7; ++b)
                wt[a][b] = rfl(Wb[c*49 + a*7 + b]);
        __syncthreads();

#pragma unroll
        for (int rr = 0; rr < 10; ++rr) {
            const float4* lp = (const float4*)&st[(hg*4 + rr)*264 + w4];
            float4 A0 = lp[0], A1 = lp[1], A2 = lp[2];
            float win[12] = {A0.x,A0.y,A0.z,A0.w, A1.x,A1.y,A1.z,A1.w,
                             A2.x,A2.y,A2.z,A2.w};
#pragma unroll
            for (int k = 0; k < 4; ++k) {
                const int a = k + 6 - rr;
                if (a >= 0 && a < 7) {
#pragma unroll
                    for (int b = 0; b < 7; ++b) {
                        float wv = wt[a][b];
#pragma unroll
                        for (int j = 0; j < 4; ++j)
                            acc[k][j] += win[j - b + 6] * wv;
                    }
                }
            }
        }
    }

#pragma unroll
    for (int k = 0; k < 4; ++k) {
        int h = h0 + hg*4 + k;
        *(float4*)(O + (size_t)h*WW + w4) =
            make_float4(acc[k][0], acc[k][1], acc[k][2], acc[k][3]);
    }
}

// ---------------------------------------------------------------------------
// k_res: reduce partials -> Xc/Uc; prev compacts = Xo/Uo; write compacts;
// emit res.
// ---------------------------------------------------------------------------
__global__ __launch_bounds__(256) void k_res(
    const float* __restrict__ y,
    const float* __restrict__ Xp, const float* __restrict__ Up,
    float* Xred, float* Ured,
    float* __restrict__ res, float cm, int nparts)
{
    int i = blockIdx.x*256 + threadIdx.x;
    if (i >= IMG_TOT/4) return;
    float4 xc = ((const float4*)Xp)[i];
    float4 uc = ((const float4*)Up)[i];
    for (int g = 1; g < nparts; ++g) {
        float4 t = ((const float4*)Xp)[(size_t)g*(IMG_TOT/4) + i];
        xc.x += t.x; xc.y += t.y; xc.z += t.z; xc.w += t.w;
        float4 s = ((const float4*)Up)[(size_t)g*(IMG_TOT/4) + i];
        uc.x += s.x; uc.y += s.y; uc.z += s.z; uc.w += s.w;
    }
    float4 xo = make_float4(0.f,0.f,0.f,0.f), uo = xo;
    if (cm != 0.0f) {
        xo = ((const float4*)Xred)[i];
        uo = ((const float4*)Ured)[i];
    }
    ((float4*)Xred)[i] = xc;
    ((float4*)Ured)[i] = uc;
    float4 yv = ((const float4*)y)[i];
    float cp = 1.0f + cm;
    float4 r;
    r.x = yv.x - ALPHA*(cp*xc.x - cm*xo.x) - (cp*uc.x - cm*uo.x);
    r.y = yv.y - ALPHA*(cp*xc.y - cm*xo.y) - (cp*uc.y - cm*uo.y);
    r.z = yv.z - ALPHA*(cp*xc.z - cm*xo.z) - (cp*uc.z - cm*uo.z);
    r.w = yv.w - ALPHA*(cp*xc.w - cm*xo.w) - (cp*uc.w - cm*uo.w);
    ((float4*)res)[i] = r;
}

// ---------------------------------------------------------------------------
// k_final: reduce gen-15 partials; yhat = X+U; Ax_hat = X; Bu_hat = U.
// ---------------------------------------------------------------------------
__global__ __launch_bounds__(256) void k_final(
    const float* Xp, const float* Up,
    float* yhat, float* axh, float* buh, int nparts)
{
    int i = blockIdx.x*256 + threadIdx.x;
    if (i >= IMG_TOT/4) return;
    float4 x = ((const float4*)Xp)[i];
    float4 u = ((const float4*)Up)[i];
    for (int g = 1; g < nparts; ++g) {
        float4 t = ((const float4*)Xp)[(size_t)g*(IMG_TOT/4) + i];
        x.x += t.x; x.y += t.y; x.z += t.z; x.w += t.w;
        float4 s = ((const float4*)Up)[(size_t)g*(IMG_TOT/4) + i];
        u.x += s.x; u.y += s.y; u.z += s.z; u.w += s.w;
    }
    float4 sm;
    sm.x = x.x + u.x; sm.y = x.y + u.y; sm.z = x.z + u.z; sm.w = x.w + u.w;
    ((float4*)yhat)[i] = sm;
    ((float4*)axh)[i]  = x;
    ((float4*)buh)[i]  = u;
}

extern "C" void kernel_launch(void* const* d_in, const int* in_sizes, int n_in,
                              void* d_out, int out_size, void* d_ws, size_t ws_size,
                              hipStream_t stream) {
    const float* y = (const float*)d_in[0];
    const float* A = (const float*)d_in[1];
    const float* B = (const float*)d_in[2];

    float* out  = (float*)d_out;
    float* yhat = out;                          // [IMG_TOT]
    float* xout = out + IMG_TOT;                // [FLD_TOT]
    float* uout = xout + FLD_TOT;               // [FLD_TOT]
    float* axh  = uout + FLD_TOT;               // [IMG_TOT]
    float* buh  = axh + IMG_TOT;                // [IMG_TOT]

    float* ws   = (float*)d_ws;
    float* Px0  = ws;                           // [FLD_TOT]
    float* Pu0  = Px0 + FLD_TOT;                // [FLD_TOT]
    float* Xred = Pu0 + FLD_TOT;                // [IMG_TOT]
    float* Ured = Xred + IMG_TOT;               // [IMG_TOT]

    int ngroups = 1;
    float* Xpart = axh;
    float* Upart = buh;
    size_t need4 = (2*FLD_TOT + 10*(size_t)IMG_TOT) * sizeof(float); // ~296 MB
    if (ws_size >= need4) {
        ngroups = 4;
        Xpart = Ured + IMG_TOT;                 // [4*IMG_TOT]
        Upart = Xpart + 4*(size_t)IMG_TOT;      // [4*IMG_TOT]
    }
    const int nc = CC / ngroups;

    float cv[15];
    {
        float t = 1.0f;
        for (int k = 0; k < 15; ++k) {
            float tn = (1.0f + sqrtf(1.0f + 4.0f*t*t)) * 0.5f;
            cv[k] = (t - 1.0f) / tn;
            t = tn;
        }
    }

    float* Px[2] = {Px0, xout};
    float* Pu[2] = {Pu0, uout};
    float* res   = yhat;

    dim3 blk(256);
    dim3 gU(64, 16, NB);                        // (channel, p-tile, n)
    dim3 gT(16, 2, NB*ngroups);                 // (h-tile, field, n*group)
    int  gE = (IMG_TOT/4 + 255)/256;

    k_update<<<gU, blk, 0, stream>>>(y, Px[0], Px[0], Pu[0], Pu[0],
                                     Px[1], Pu[1], A, B, 0.0f, 1);
    k_convT<<<gT, blk, 0, stream>>>(Px[1], Pu[1], Xpart, Upart, A, B, nc, ngroups);

    for (int t = 1; t < 15; ++t) {
        int cur = t & 1, nxt = cur ^ 1;
        float cm = cv[t-1];
        k_res<<<gE, blk, 0, stream>>>(y, Xpart, Upart, Xred, Ured, res, cm, ngroups);
        k_update<<<gU, blk, 0, stream>>>(res, Px[cur], Px[nxt], Pu[cur], Pu[nxt],
                                         Px[nxt], Pu[nxt], A, B, cm, 0);
        k_convT<<<gT, blk, 0, stream>>>(Px[nxt], Pu[nxt], Xpart, Upart, A, B, nc, ngroups);
    }

    k_final<<<gE, blk, 0, stream>>>(Xpart, Upart, yhat, axh, buh, ngroups);
}